// Round 1
// baseline (1165.616 us; speedup 1.0000x reference)
//
#include <hip/hip_runtime.h>
#include <math.h>

// Problem constants
constexpr int kB = 2;
constexpr int kS = 2048;
constexpr int kC = 1024;
constexpr int kH = 16;
constexpr int kD = 64;
constexpr int kF = 3072;
constexpr int kT = kB * kS;  // 4096 tokens

// ---------------------------------------------------------------------------
// Kernel 1: qkv = x @ W_qkv + b_qkv, fused RoPE on q,k, scatter to [B,H,S,D].
// 64x64 block tile, 256 threads, 4x4 microtile, K-step 16.
// ---------------------------------------------------------------------------
__global__ __launch_bounds__(256) void qkv_rope_kernel(
    const float* __restrict__ x, const float* __restrict__ w,
    const float* __restrict__ bias, const float* __restrict__ freqs,
    float* __restrict__ qg, float* __restrict__ kg, float* __restrict__ vg)
{
    __shared__ float As[16][68];  // [kk][m], padded (write 2-way, read free)
    __shared__ float Bs[16][68];  // [kk][n]
    const int tid = threadIdx.x;
    const int tx = tid & 15, ty = tid >> 4;
    const int m0 = blockIdx.y * 64;
    const int n0 = blockIdx.x * 64;
    const int am = tid >> 2, ak = (tid & 3) * 4;
    const int bk = tid >> 4, bn = (tid & 15) * 4;
    float acc[4][4] = {};
    for (int kt = 0; kt < kC; kt += 16) {
        float4 av = *reinterpret_cast<const float4*>(&x[(size_t)(m0 + am) * kC + kt + ak]);
        float4 bv = *reinterpret_cast<const float4*>(&w[(size_t)(kt + bk) * kF + n0 + bn]);
        As[ak + 0][am] = av.x;
        As[ak + 1][am] = av.y;
        As[ak + 2][am] = av.z;
        As[ak + 3][am] = av.w;
        *reinterpret_cast<float4*>(&Bs[bk][bn]) = bv;
        __syncthreads();
#pragma unroll
        for (int kk = 0; kk < 16; ++kk) {
            float4 a4 = *reinterpret_cast<const float4*>(&As[kk][ty * 4]);
            float4 b4 = *reinterpret_cast<const float4*>(&Bs[kk][tx * 4]);
            const float ar[4] = {a4.x, a4.y, a4.z, a4.w};
            const float br[4] = {b4.x, b4.y, b4.z, b4.w};
#pragma unroll
            for (int i = 0; i < 4; ++i)
#pragma unroll
                for (int j = 0; j < 4; ++j)
                    acc[i][j] = fmaf(ar[i], br[j], acc[i][j]);
        }
        __syncthreads();
    }
    // Epilogue: bias + RoPE + scatter. Columns [n0+tx*4, +4) share which/head.
    const int ncol = n0 + tx * 4;
    const int which = ncol >> 10;          // 0=q 1=k 2=v
    const int rem = ncol & 1023;
    const int hh = rem >> 6;
    const int d0 = rem & 63;               // d0 % 4 == 0
    float* dst = (which == 0) ? qg : ((which == 1) ? kg : vg);
    const float b0 = bias[ncol + 0], b1 = bias[ncol + 1];
    const float b2 = bias[ncol + 2], b3 = bias[ncol + 3];
#pragma unroll
    for (int i = 0; i < 4; ++i) {
        const int r = m0 + ty * 4 + i;     // token index
        const int bb = r >> 11;
        const int s = r & 2047;
        float c0 = acc[i][0] + b0, c1 = acc[i][1] + b1;
        float c2 = acc[i][2] + b2, c3 = acc[i][3] + b3;
        if (which < 2) {
            const int p0 = d0 >> 1;        // pair index for (c0,c1); (c2,c3) is p0+1
            const float f0 = freqs[s * (kD / 2) + p0];
            const float f1 = freqs[s * (kD / 2) + p0 + 1];
            float sn0, cs0, sn1, cs1;
            sincosf(f0, &sn0, &cs0);
            sincosf(f1, &sn1, &cs1);
            const float o0 = c0 * cs0 - c1 * sn0;
            const float o1 = c0 * sn0 + c1 * cs0;
            const float o2 = c2 * cs1 - c3 * sn1;
            const float o3 = c2 * sn1 + c3 * cs1;
            c0 = o0; c1 = o1; c2 = o2; c3 = o3;
        }
        *reinterpret_cast<float4*>(&dst[((size_t)(bb * kH + hh) * kS + s) * kD + d0]) =
            make_float4(c0, c1, c2, c3);
    }
}

// ---------------------------------------------------------------------------
// Kernel 2: flash attention, f32. One block = (b,h) x 64 q-rows.
// Online softmax; 16-lane shuffle row-reductions. LDS = 64 KB exactly.
// ---------------------------------------------------------------------------
__global__ __launch_bounds__(256) void attn_kernel(
    const float* __restrict__ qg, const float* __restrict__ kg,
    const float* __restrict__ vg, float* __restrict__ og)
{
    __shared__ float Qt[64][64];  // [dd][qr]  (transposed)
    __shared__ float Kt[64][64];  // [dd][key] (transposed)
    __shared__ float Vs[64][64];  // [key][dd] (natural)
    __shared__ float Ps[64][64];  // [key][qr] (transposed)
    const int tid = threadIdx.x;
    const int tx = tid & 15, ty = tid >> 4;
    const int q0 = blockIdx.x * 64;
    const int bh = blockIdx.y;
    const float* qb = qg + (size_t)bh * kS * kD;
    const float* kb = kg + (size_t)bh * kS * kD;
    const float* vb = vg + (size_t)bh * kS * kD;
    const int lr = tid >> 4;           // 0..15
    const int ld0 = (tid & 15) * 4;    // 0..60
#pragma unroll
    for (int rr = 0; rr < 64; rr += 16) {
        float4 t = *reinterpret_cast<const float4*>(&qb[(size_t)(q0 + lr + rr) * kD + ld0]);
        Qt[ld0 + 0][lr + rr] = t.x;
        Qt[ld0 + 1][lr + rr] = t.y;
        Qt[ld0 + 2][lr + rr] = t.z;
        Qt[ld0 + 3][lr + rr] = t.w;
    }
    float m_i[4], l_i[4], o[4][4] = {};
#pragma unroll
    for (int i = 0; i < 4; ++i) { m_i[i] = -INFINITY; l_i[i] = 0.f; }

    for (int kt = 0; kt < kS; kt += 64) {
        __syncthreads();  // previous tile's readers done before overwrite (also orders Qt on iter 0)
#pragma unroll
        for (int rr = 0; rr < 64; rr += 16) {
            float4 t = *reinterpret_cast<const float4*>(&kb[(size_t)(kt + lr + rr) * kD + ld0]);
            Kt[ld0 + 0][lr + rr] = t.x;
            Kt[ld0 + 1][lr + rr] = t.y;
            Kt[ld0 + 2][lr + rr] = t.z;
            Kt[ld0 + 3][lr + rr] = t.w;
            float4 u = *reinterpret_cast<const float4*>(&vb[(size_t)(kt + lr + rr) * kD + ld0]);
            *reinterpret_cast<float4*>(&Vs[lr + rr][ld0]) = u;
        }
        __syncthreads();
        // scores: S = Q K^T  (per-thread 4x4 over [q rows ty*4..][keys tx*4..])
        float acc[4][4] = {};
#pragma unroll 16
        for (int kk = 0; kk < 64; ++kk) {
            float4 a4 = *reinterpret_cast<const float4*>(&Qt[kk][ty * 4]);
            float4 b4 = *reinterpret_cast<const float4*>(&Kt[kk][tx * 4]);
            const float ar[4] = {a4.x, a4.y, a4.z, a4.w};
            const float br[4] = {b4.x, b4.y, b4.z, b4.w};
#pragma unroll
            for (int i = 0; i < 4; ++i)
#pragma unroll
                for (int j = 0; j < 4; ++j)
                    acc[i][j] = fmaf(ar[i], br[j], acc[i][j]);
        }
        // online softmax
        float pr[4][4];
#pragma unroll
        for (int i = 0; i < 4; ++i) {
            float mx = -INFINITY;
#pragma unroll
            for (int j = 0; j < 4; ++j) {
                acc[i][j] *= 0.125f;  // 1/sqrt(64)
                mx = fmaxf(mx, acc[i][j]);
            }
#pragma unroll
            for (int off = 1; off < 16; off <<= 1) mx = fmaxf(mx, __shfl_xor(mx, off));
            const float mnew = fmaxf(m_i[i], mx);
            const float alpha = __expf(m_i[i] - mnew);  // exp(-inf)=0 on first tile
            m_i[i] = mnew;
            float rs = 0.f;
#pragma unroll
            for (int j = 0; j < 4; ++j) {
                const float p = __expf(acc[i][j] - mnew);
                pr[i][j] = p;
                rs += p;
            }
#pragma unroll
            for (int off = 1; off < 16; off <<= 1) rs += __shfl_xor(rs, off);
            l_i[i] = l_i[i] * alpha + rs;
#pragma unroll
            for (int j = 0; j < 4; ++j) o[i][j] *= alpha;
        }
#pragma unroll
        for (int j = 0; j < 4; ++j)
#pragma unroll
            for (int i = 0; i < 4; ++i)
                Ps[tx * 4 + j][ty * 4 + i] = pr[i][j];
        __syncthreads();
        // O += P V
#pragma unroll 16
        for (int kk = 0; kk < 64; ++kk) {
            float4 a4 = *reinterpret_cast<const float4*>(&Ps[kk][ty * 4]);
            float4 b4 = *reinterpret_cast<const float4*>(&Vs[kk][tx * 4]);
            const float ar[4] = {a4.x, a4.y, a4.z, a4.w};
            const float br[4] = {b4.x, b4.y, b4.z, b4.w};
#pragma unroll
            for (int i = 0; i < 4; ++i)
#pragma unroll
                for (int j = 0; j < 4; ++j)
                    o[i][j] = fmaf(ar[i], br[j], o[i][j]);
        }
    }
    // epilogue: normalize and write [B,S,C] token-major
    const int bb = bh >> 4, hh = bh & 15;
#pragma unroll
    for (int i = 0; i < 4; ++i) {
        const int s = q0 + ty * 4 + i;
        const float inv = 1.f / l_i[i];
        *reinterpret_cast<float4*>(
            &og[((size_t)(bb * kS + s)) * kC + hh * kD + tx * 4]) =
            make_float4(o[i][0] * inv, o[i][1] * inv, o[i][2] * inv, o[i][3] * inv);
    }
}

// ---------------------------------------------------------------------------
// Kernel 3: out = attn_out @ W_out + b_out   (M=4096, N=1024, K=1024)
// ---------------------------------------------------------------------------
__global__ __launch_bounds__(256) void out_gemm_kernel(
    const float* __restrict__ a, const float* __restrict__ w,
    const float* __restrict__ bias, float* __restrict__ out)
{
    __shared__ float As[16][68];
    __shared__ float Bs[16][68];
    const int tid = threadIdx.x;
    const int tx = tid & 15, ty = tid >> 4;
    const int m0 = blockIdx.y * 64;
    const int n0 = blockIdx.x * 64;
    const int am = tid >> 2, ak = (tid & 3) * 4;
    const int bk = tid >> 4, bn = (tid & 15) * 4;
    float acc[4][4] = {};
    for (int kt = 0; kt < kC; kt += 16) {
        float4 av = *reinterpret_cast<const float4*>(&a[(size_t)(m0 + am) * kC + kt + ak]);
        float4 bv = *reinterpret_cast<const float4*>(&w[(size_t)(kt + bk) * kC + n0 + bn]);
        As[ak + 0][am] = av.x;
        As[ak + 1][am] = av.y;
        As[ak + 2][am] = av.z;
        As[ak + 3][am] = av.w;
        *reinterpret_cast<float4*>(&Bs[bk][bn]) = bv;
        __syncthreads();
#pragma unroll
        for (int kk = 0; kk < 16; ++kk) {
            float4 a4 = *reinterpret_cast<const float4*>(&As[kk][ty * 4]);
            float4 b4 = *reinterpret_cast<const float4*>(&Bs[kk][tx * 4]);
            const float ar[4] = {a4.x, a4.y, a4.z, a4.w};
            const float br[4] = {b4.x, b4.y, b4.z, b4.w};
#pragma unroll
            for (int i = 0; i < 4; ++i)
#pragma unroll
                for (int j = 0; j < 4; ++j)
                    acc[i][j] = fmaf(ar[i], br[j], acc[i][j]);
        }
        __syncthreads();
    }
    const int ncol = n0 + tx * 4;
    const float b0 = bias[ncol + 0], b1 = bias[ncol + 1];
    const float b2 = bias[ncol + 2], b3 = bias[ncol + 3];
#pragma unroll
    for (int i = 0; i < 4; ++i) {
        const int r = m0 + ty * 4 + i;
        *reinterpret_cast<float4*>(&out[(size_t)r * kC + ncol]) =
            make_float4(acc[i][0] + b0, acc[i][1] + b1, acc[i][2] + b2, acc[i][3] + b3);
    }
}

// ---------------------------------------------------------------------------
extern "C" void kernel_launch(void* const* d_in, const int* in_sizes, int n_in,
                              void* d_out, int out_size, void* d_ws, size_t ws_size,
                              hipStream_t stream) {
    const float* x     = (const float*)d_in[0];
    const float* freqs = (const float*)d_in[1];
    const float* W_qkv = (const float*)d_in[2];
    const float* b_qkv = (const float*)d_in[3];
    const float* W_out = (const float*)d_in[4];
    const float* b_out = (const float*)d_in[5];
    float* out = (float*)d_out;
    float* ws = (float*)d_ws;

    const size_t per = (size_t)kB * kH * kS * kD;  // 4,194,304 floats
    float* qg = ws;
    float* kg = ws + per;
    float* vg = ws + 2 * per;
    float* ag = ws + 3 * per;  // attention output, [B,S,C] token-major

    dim3 blk(256);
    qkv_rope_kernel<<<dim3(kF / 64, kT / 64), blk, 0, stream>>>(x, W_qkv, b_qkv, freqs, qg, kg, vg);
    attn_kernel<<<dim3(kS / 64, kB * kH), blk, 0, stream>>>(qg, kg, vg, ag);
    out_gemm_kernel<<<dim3(kC / 64, kT / 64), blk, 0, stream>>>(ag, W_out, b_out, out);
}

// Round 2
// 233.749 us; speedup vs baseline: 4.9866x; 4.9866x over previous
//
#include <hip/hip_runtime.h>
#include <math.h>

// Problem constants
constexpr int kB = 2;
constexpr int kS = 2048;
constexpr int kC = 1024;
constexpr int kH = 16;
constexpr int kD = 64;
constexpr int kF = 3072;
constexpr int kT = kB * kS;  // 4096 tokens

typedef __attribute__((ext_vector_type(8))) short short8v;   // 8 bf16 (4 VGPR)
typedef __attribute__((ext_vector_type(4))) short short4v;
typedef __attribute__((ext_vector_type(4))) float f32x4;

__device__ __forceinline__ short f2bf(float f) {
    unsigned u = __builtin_bit_cast(unsigned, f);
    u += 0x7fffu + ((u >> 16) & 1u);   // RNE
    return (short)(u >> 16);
}

__device__ __forceinline__ void gl_lds16(const void* g, void* l) {
    __builtin_amdgcn_global_load_lds(
        (const __attribute__((address_space(1))) char*)g,
        (__attribute__((address_space(3))) char*)l, 16, 0, 0);
}

__device__ __forceinline__ f32x4 mfma16(short8v a, short8v b, f32x4 c) {
    return __builtin_amdgcn_mfma_f32_16x16x32_bf16(a, b, c, 0, 0, 0);
}

// ---------------------------------------------------------------------------
// Prepass kernels
// ---------------------------------------------------------------------------
__global__ __launch_bounds__(256) void cvt_x_kernel(const float* __restrict__ in,
                                                    short* __restrict__ out, int n4) {
    int i = blockIdx.x * 256 + threadIdx.x;
    if (i < n4) {
        float4 v = reinterpret_cast<const float4*>(in)[i];
        short4v o = { f2bf(v.x), f2bf(v.y), f2bf(v.z), f2bf(v.w) };
        reinterpret_cast<short4v*>(out)[i] = o;
    }
}

// W [K][N] f32  ->  Wt [N][K] bf16
__global__ __launch_bounds__(256) void tcvt_kernel(const float* __restrict__ w,
                                                   short* __restrict__ wt, int K, int N) {
    __shared__ float Ts[64][65];
    const int t = threadIdx.x;
    const int n0 = blockIdx.x * 64, k0 = blockIdx.y * 64;
    const int r = t >> 4, c4 = (t & 15) * 4;
#pragma unroll
    for (int rr = 0; rr < 64; rr += 16) {
        float4 v = *reinterpret_cast<const float4*>(&w[(size_t)(k0 + r + rr) * N + n0 + c4]);
        Ts[r + rr][c4 + 0] = v.x; Ts[r + rr][c4 + 1] = v.y;
        Ts[r + rr][c4 + 2] = v.z; Ts[r + rr][c4 + 3] = v.w;
    }
    __syncthreads();
#pragma unroll
    for (int rr = 0; rr < 64; rr += 16) {
        int n = r + rr;
        short4v o = { f2bf(Ts[c4 + 0][n]), f2bf(Ts[c4 + 1][n]),
                      f2bf(Ts[c4 + 2][n]), f2bf(Ts[c4 + 3][n]) };
        *reinterpret_cast<short4v*>(&wt[(size_t)(n0 + n) * K + k0 + c4]) = o;
    }
}

__global__ __launch_bounds__(256) void rope_tab_kernel(const float* __restrict__ freqs,
                                                       float* __restrict__ cost,
                                                       float* __restrict__ sint) {
    int i = blockIdx.x * 256 + threadIdx.x;  // < kS * kD/2 = 65536
    float f = freqs[i];
    float s, c;
    sincosf(f, &s, &c);
    cost[i] = c; sint[i] = s;
}

// ---------------------------------------------------------------------------
// Shared MFMA GEMM mainloop: C[128x128] tile, A [M][1024] bf16 row-major,
// Bt [N][1024] bf16 (pre-transposed weights). BK=64, 4 waves, 64x64/wave.
// LDS staged via global_load_lds with XOR-chunk swizzle (conflict-free b128).
// ---------------------------------------------------------------------------
__device__ __forceinline__ void gemm_main(const short* __restrict__ A,
                                          const short* __restrict__ Bt,
                                          int m0, int n0, short* Als, short* Bls,
                                          f32x4 acc[4][4]) {
    const int tid = threadIdx.x, wid = tid >> 6, lane = tid & 63;
    const int srow = lane >> 3, schunk = lane & 7;
    const int fr = lane & 15, fg = lane >> 4;
    const int wm = (wid >> 1) * 64, wn = (wid & 1) * 64;
    for (int kt = 0; kt < 1024; kt += 64) {
        __syncthreads();
#pragma unroll
        for (int j = 0; j < 4; ++j) {
            int i = wid * 4 + j;
            int row = i * 8 + srow;
            gl_lds16(&A[(size_t)(m0 + row) * 1024 + kt + ((schunk ^ (row & 7)) << 3)],
                     &Als[i * 512]);
        }
#pragma unroll
        for (int j = 0; j < 4; ++j) {
            int i = wid * 4 + j;
            int row = i * 8 + srow;
            gl_lds16(&Bt[(size_t)(n0 + row) * 1024 + kt + ((schunk ^ (row & 7)) << 3)],
                     &Bls[i * 512]);
        }
        __syncthreads();
#pragma unroll
        for (int kk = 0; kk < 2; ++kk) {
            short8v af[4], bf[4];
#pragma unroll
            for (int fm = 0; fm < 4; ++fm) {
                int row = wm + fm * 16 + fr;
                af[fm] = *reinterpret_cast<const short8v*>(
                    &Als[row * 64 + (((fg + 4 * kk) ^ (row & 7)) << 3)]);
            }
#pragma unroll
            for (int fn = 0; fn < 4; ++fn) {
                int row = wn + fn * 16 + fr;
                bf[fn] = *reinterpret_cast<const short8v*>(
                    &Bls[row * 64 + (((fg + 4 * kk) ^ (row & 7)) << 3)]);
            }
#pragma unroll
            for (int fm = 0; fm < 4; ++fm)
#pragma unroll
                for (int fn = 0; fn < 4; ++fn)
                    acc[fm][fn] = mfma16(af[fm], bf[fn], acc[fm][fn]);
        }
    }
}

// ---------------------------------------------------------------------------
// Kernel: qkv = x @ W_qkv + b, fused RoPE(q,k), q pre-scaled by 1/8.
// q,k -> [B,H,S,D] bf16 ; v -> [B,H,D,S] bf16 (transposed for PV B-frags)
// ---------------------------------------------------------------------------
__global__ __launch_bounds__(256) void qkv_gemm_kernel(
    const short* __restrict__ xb, const short* __restrict__ wqt,
    const float* __restrict__ bias, const float* __restrict__ cost,
    const float* __restrict__ sint,
    short* __restrict__ qg, short* __restrict__ kg, short* __restrict__ vt) {
    __shared__ __attribute__((aligned(16))) short Als[128 * 64];
    __shared__ __attribute__((aligned(16))) short Bls[128 * 64];
    f32x4 acc[4][4] = {};
    const int tid = threadIdx.x, wid = tid >> 6, lane = tid & 63;
    const int m0 = blockIdx.y * 128, n0 = blockIdx.x * 128;
    gemm_main(xb, wqt, m0, n0, Als, Bls, acc);

    const int fr = lane & 15, fg = lane >> 4;
    const int wm = (wid >> 1) * 64, wn = (wid & 1) * 64;
    const int which = (n0 + wn) >> 10;   // 0=q 1=k 2=v (uniform per block)
    const int bidx = m0 >> 11;
#pragma unroll
    for (int fn = 0; fn < 4; ++fn) {
        int col = n0 + wn + fn * 16 + fr;
        float bv = bias[col];
        int d = col & 63;
        int h = (col >> 6) & 15;
        int p0 = d >> 1;
        int odd = d & 1;
#pragma unroll
        for (int fm = 0; fm < 4; ++fm) {
            int r0 = m0 + wm + fm * 16 + fg * 4;
            int s0 = r0 & 2047;
            float c[4];
#pragma unroll
            for (int r = 0; r < 4; ++r) c[r] = acc[fm][fn][r] + bv;
            if (which < 2) {
#pragma unroll
                for (int r = 0; r < 4; ++r) {
                    float cs = cost[(s0 + r) * 32 + p0];
                    float sn = sint[(s0 + r) * 32 + p0];
                    float p = __shfl_xor(c[r], 1);   // partner of the rope pair
                    float o = odd ? fmaf(p, sn, c[r] * cs) : fmaf(-p, sn, c[r] * cs);
                    c[r] = (which == 0) ? o * 0.125f : o;   // fold 1/sqrt(D) into q
                }
                short* dst = which ? kg : qg;
                size_t base = ((size_t)(bidx * 16 + h) * 2048 + s0) * 64 + d;
#pragma unroll
                for (int r = 0; r < 4; ++r) dst[base + (size_t)r * 64] = f2bf(c[r]);
            } else {
                short4v o = { f2bf(c[0]), f2bf(c[1]), f2bf(c[2]), f2bf(c[3]) };
                *reinterpret_cast<short4v*>(
                    &vt[((size_t)(bidx * 16 + h) * 64 + d) * 2048 + s0]) = o;
            }
        }
    }
}

// ---------------------------------------------------------------------------
// Kernel: MFMA flash attention. Block = (b,h) x 128 q-rows, 4 waves x 32 rows.
// KVBLK=128; K,V staged swizzled via global_load_lds; per-wave P via LDS.
// Writes attention output as bf16 [B,S,C] (A of the out-projection GEMM).
// ---------------------------------------------------------------------------
__global__ __launch_bounds__(256) void attn_mfma_kernel(
    const short* __restrict__ qg, const short* __restrict__ kg,
    const short* __restrict__ vt, short* __restrict__ ab) {
    __shared__ __attribute__((aligned(16))) short Kls[128 * 64];     // [key][d]
    __shared__ __attribute__((aligned(16))) short Vls[64 * 128];     // [d][key]
    __shared__ __attribute__((aligned(16))) short Pls[4][32 * 128];  // per-wave [q][key]
    const int tid = threadIdx.x, wid = tid >> 6, lane = tid & 63;
    const int fr = lane & 15, fg = lane >> 4;
    const int bh = blockIdx.y;
    const int qw = blockIdx.x * 128 + wid * 32;
    const short* qb = qg + (size_t)bh * 2048 * 64;
    const short* kb = kg + (size_t)bh * 2048 * 64;
    const short* vb = vt + (size_t)bh * 64 * 2048;

    short8v qf[2][2];
#pragma unroll
    for (int mq = 0; mq < 2; ++mq) {
        int row = qw + mq * 16 + fr;
        const short* p = &qb[(size_t)row * 64 + fg * 8];
        qf[mq][0] = *reinterpret_cast<const short8v*>(p);
        qf[mq][1] = *reinterpret_cast<const short8v*>(p + 32);
    }
    float m_i[2][4], l_i[2][4];
    f32x4 o[2][4] = {};
#pragma unroll
    for (int mq = 0; mq < 2; ++mq)
#pragma unroll
        for (int r = 0; r < 4; ++r) { m_i[mq][r] = -INFINITY; l_i[mq][r] = 0.f; }

    const int srow8 = lane >> 3, sc8 = lane & 7;
    short* P = &Pls[wid][0];

    for (int kt = 0; kt < 2048; kt += 128) {
        __syncthreads();   // all waves done reading K/V of previous tile
#pragma unroll
        for (int j = 0; j < 4; ++j) {        // K tile: 128 rows x 64d
            int i = wid * 4 + j;
            int row = i * 8 + srow8;
            gl_lds16(&kb[(size_t)(kt + row) * 64 + ((sc8 ^ (row & 7)) << 3)], &Kls[i * 512]);
        }
#pragma unroll
        for (int j = 0; j < 4; ++j) {        // V tile: 64 d-rows x 128 keys
            int i = wid * 4 + j;
            int d = i * 4 + fg;
            gl_lds16(&vb[(size_t)d * 2048 + kt + ((fr ^ (d & 7)) << 3)], &Vls[i * 512]);
        }
        __syncthreads();

        // S = Q K^T   (q pre-scaled by 1/8 at qkv epilogue)
        f32x4 sacc[2][8] = {};
#pragma unroll
        for (int f = 0; f < 8; ++f)
#pragma unroll
            for (int kk = 0; kk < 2; ++kk) {
                int key = f * 16 + fr;
                short8v kf = *reinterpret_cast<const short8v*>(
                    &Kls[key * 64 + (((fg + 4 * kk) ^ (key & 7)) << 3)]);
#pragma unroll
                for (int mq = 0; mq < 2; ++mq)
                    sacc[mq][f] = mfma16(qf[mq][kk], kf, sacc[mq][f]);
            }

        // online softmax (rows live in lanes: row = fg*4+r, cols = 16f+fr)
#pragma unroll
        for (int mq = 0; mq < 2; ++mq) {
            float al[4];
#pragma unroll
            for (int r = 0; r < 4; ++r) {
                float mx = sacc[mq][0][r];
#pragma unroll
                for (int f = 1; f < 8; ++f) mx = fmaxf(mx, sacc[mq][f][r]);
                mx = fmaxf(mx, __shfl_xor(mx, 1));
                mx = fmaxf(mx, __shfl_xor(mx, 2));
                mx = fmaxf(mx, __shfl_xor(mx, 4));
                mx = fmaxf(mx, __shfl_xor(mx, 8));
                float mn = fmaxf(m_i[mq][r], mx);
                al[r] = __expf(m_i[mq][r] - mn);
                m_i[mq][r] = mn;
            }
            float rs[4] = {0.f, 0.f, 0.f, 0.f};
#pragma unroll
            for (int f = 0; f < 8; ++f)
#pragma unroll
                for (int r = 0; r < 4; ++r) {
                    float p = __expf(sacc[mq][f][r] - m_i[mq][r]);
                    sacc[mq][f][r] = p;
                    rs[r] += p;
                }
#pragma unroll
            for (int r = 0; r < 4; ++r) {
                rs[r] += __shfl_xor(rs[r], 1);
                rs[r] += __shfl_xor(rs[r], 2);
                rs[r] += __shfl_xor(rs[r], 4);
                rs[r] += __shfl_xor(rs[r], 8);
                l_i[mq][r] = l_i[mq][r] * al[r] + rs[r];
            }
#pragma unroll
            for (int fd = 0; fd < 4; ++fd)
#pragma unroll
                for (int r = 0; r < 4; ++r) o[mq][fd][r] *= al[r];
            // write P (bf16) into per-wave swizzled LDS (no barrier needed)
#pragma unroll
            for (int f = 0; f < 8; ++f)
#pragma unroll
                for (int r = 0; r < 4; ++r) {
                    int q = mq * 16 + fg * 4 + r;
                    int key = f * 16 + fr;
                    int chunk = key >> 3;
                    int lo = (2 * key) & 15;
                    int sw = (((chunk ^ (q & 7)) & 15) << 4) | lo;
                    P[q * 128 + (sw >> 1)] = f2bf(sacc[mq][f][r]);
                }
        }

        // O += P V
#pragma unroll
        for (int kk2 = 0; kk2 < 4; ++kk2) {
            short8v pa[2];
#pragma unroll
            for (int mq = 0; mq < 2; ++mq) {
                int q = mq * 16 + fr;
                pa[mq] = *reinterpret_cast<const short8v*>(
                    &P[q * 128 + (((fg + 4 * kk2) ^ (q & 7)) << 3)]);
            }
#pragma unroll
            for (int fd = 0; fd < 4; ++fd) {
                int d = fd * 16 + fr;
                short8v vf = *reinterpret_cast<const short8v*>(
                    &Vls[d * 128 + (((fg + 4 * kk2) ^ (d & 7)) << 3)]);
#pragma unroll
                for (int mq = 0; mq < 2; ++mq)
                    o[mq][fd] = mfma16(pa[mq], vf, o[mq][fd]);
            }
        }
    }

    // epilogue: normalize, write bf16 [B,S,C]
    const int hh = bh & 15, bb = bh >> 4;
#pragma unroll
    for (int mq = 0; mq < 2; ++mq)
#pragma unroll
        for (int r = 0; r < 4; ++r) {
            int s = qw + mq * 16 + fg * 4 + r;
            float inv = 1.f / l_i[mq][r];
#pragma unroll
            for (int fd = 0; fd < 4; ++fd) {
                int col = hh * 64 + fd * 16 + fr;
                ab[(size_t)(bb * 2048 + s) * 1024 + col] = f2bf(o[mq][fd][r] * inv);
            }
        }
}

// ---------------------------------------------------------------------------
// Kernel: out = attn_out @ W_out + b_out  (f32 output)
// ---------------------------------------------------------------------------
__global__ __launch_bounds__(256) void out_gemm_kernel(
    const short* __restrict__ ab, const short* __restrict__ wot,
    const float* __restrict__ bias, float* __restrict__ out) {
    __shared__ __attribute__((aligned(16))) short Als[128 * 64];
    __shared__ __attribute__((aligned(16))) short Bls[128 * 64];
    f32x4 acc[4][4] = {};
    const int tid = threadIdx.x, wid = tid >> 6, lane = tid & 63;
    const int m0 = blockIdx.y * 128, n0 = blockIdx.x * 128;
    gemm_main(ab, wot, m0, n0, Als, Bls, acc);
    const int fr = lane & 15, fg = lane >> 4;
    const int wm = (wid >> 1) * 64, wn = (wid & 1) * 64;
#pragma unroll
    for (int fn = 0; fn < 4; ++fn) {
        int col = n0 + wn + fn * 16 + fr;
        float bv = bias[col];
#pragma unroll
        for (int fm = 0; fm < 4; ++fm) {
            int r0 = m0 + wm + fm * 16 + fg * 4;
#pragma unroll
            for (int r = 0; r < 4; ++r)
                out[(size_t)(r0 + r) * 1024 + col] = acc[fm][fn][r] + bv;
        }
    }
}

// ---------------------------------------------------------------------------
extern "C" void kernel_launch(void* const* d_in, const int* in_sizes, int n_in,
                              void* d_out, int out_size, void* d_ws, size_t ws_size,
                              hipStream_t stream) {
    const float* x     = (const float*)d_in[0];
    const float* freqs = (const float*)d_in[1];
    const float* W_qkv = (const float*)d_in[2];
    const float* b_qkv = (const float*)d_in[3];
    const float* W_out = (const float*)d_in[4];
    const float* b_out = (const float*)d_in[5];
    float* out = (float*)d_out;

    char* w = (char*)d_ws;
    short* xb  = (short*)w;  w += (size_t)kT * kC * 2;          // 8 MiB
    short* wqt = (short*)w;  w += (size_t)kF * kC * 2;          // 6 MiB
    short* wot = (short*)w;  w += (size_t)kC * kC * 2;          // 2 MiB
    short* qgw = (short*)w;  w += (size_t)kB * kH * kS * kD * 2;
    short* kgw = (short*)w;  w += (size_t)kB * kH * kS * kD * 2;
    short* vtw = (short*)w;  w += (size_t)kB * kH * kS * kD * 2;
    short* abw = (short*)w;  w += (size_t)kT * kC * 2;
    float* costt = (float*)w; w += (size_t)kS * (kD / 2) * 4;
    float* sintt = (float*)w; w += (size_t)kS * (kD / 2) * 4;

    cvt_x_kernel<<<dim3(kT * kC / 1024), 256, 0, stream>>>(x, xb, kT * kC / 4);
    tcvt_kernel<<<dim3(kF / 64, kC / 64), 256, 0, stream>>>(W_qkv, wqt, kC, kF);
    tcvt_kernel<<<dim3(kC / 64, kC / 64), 256, 0, stream>>>(W_out, wot, kC, kC);
    rope_tab_kernel<<<dim3(kS * (kD / 2) / 256), 256, 0, stream>>>(freqs, costt, sintt);

    qkv_gemm_kernel<<<dim3(kF / 128, kT / 128), 256, 0, stream>>>(
        xb, wqt, b_qkv, costt, sintt, qgw, kgw, vtw);
    attn_mfma_kernel<<<dim3(kS / 128, kB * kH), 256, 0, stream>>>(qgw, kgw, vtw, abw);
    out_gemm_kernel<<<dim3(kC / 128, kT / 128), 256, 0, stream>>>(abw, wot, b_out, out);
}

// Round 4
// 159.423 us; speedup vs baseline: 7.3115x; 1.4662x over previous
//
#include <hip/hip_runtime.h>
#include <math.h>

// Problem constants
constexpr int kB = 2;
constexpr int kS = 2048;
constexpr int kC = 1024;
constexpr int kH = 16;
constexpr int kD = 64;
constexpr int kF = 3072;
constexpr int kT = kB * kS;  // 4096 tokens

typedef __attribute__((ext_vector_type(8))) short short8v;   // 8 bf16 (4 VGPR)
typedef __attribute__((ext_vector_type(4))) short short4v;
typedef __attribute__((ext_vector_type(4))) float f32x4;
typedef __attribute__((ext_vector_type(16))) float f32x16;

__device__ __forceinline__ short f2bf(float f) {
    unsigned u = __builtin_bit_cast(unsigned, f);
    u += 0x7fffu + ((u >> 16) & 1u);   // RNE
    return (short)(u >> 16);
}

// packed f32x2 -> bf16x2 in one u32 (pure integer RNE, no struct types)
__device__ __forceinline__ unsigned pk_bf16(float a, float b) {
    unsigned ua = __builtin_bit_cast(unsigned, a);
    ua += 0x7fffu + ((ua >> 16) & 1u);
    unsigned ub = __builtin_bit_cast(unsigned, b);
    ub += 0x7fffu + ((ub >> 16) & 1u);
    return (ua >> 16) | (ub & 0xffff0000u);
}

__device__ __forceinline__ void gl_lds16(const void* g, void* l) {
    __builtin_amdgcn_global_load_lds(
        (const __attribute__((address_space(1))) char*)g,
        (__attribute__((address_space(3))) char*)l, 16, 0, 0);
}

__device__ __forceinline__ f32x4 mfma16(short8v a, short8v b, f32x4 c) {
    return __builtin_amdgcn_mfma_f32_16x16x32_bf16(a, b, c, 0, 0, 0);
}
__device__ __forceinline__ f32x16 mfma32(short8v a, short8v b, f32x16 c) {
    return __builtin_amdgcn_mfma_f32_32x32x16_bf16(a, b, c, 0, 0, 0);
}

// ---------------------------------------------------------------------------
// Prepass kernels
// ---------------------------------------------------------------------------
__global__ __launch_bounds__(256) void cvt_x_kernel(const float* __restrict__ in,
                                                    short* __restrict__ out, int n4) {
    int i = blockIdx.x * 256 + threadIdx.x;
    if (i < n4) {
        float4 v = reinterpret_cast<const float4*>(in)[i];
        short4v o = { f2bf(v.x), f2bf(v.y), f2bf(v.z), f2bf(v.w) };
        reinterpret_cast<short4v*>(out)[i] = o;
    }
}

// W [K][N] f32  ->  Wt [N][K] bf16
__global__ __launch_bounds__(256) void tcvt_kernel(const float* __restrict__ w,
                                                   short* __restrict__ wt, int K, int N) {
    __shared__ float Ts[64][65];
    const int t = threadIdx.x;
    const int n0 = blockIdx.x * 64, k0 = blockIdx.y * 64;
    const int r = t >> 4, c4 = (t & 15) * 4;
#pragma unroll
    for (int rr = 0; rr < 64; rr += 16) {
        float4 v = *reinterpret_cast<const float4*>(&w[(size_t)(k0 + r + rr) * N + n0 + c4]);
        Ts[r + rr][c4 + 0] = v.x; Ts[r + rr][c4 + 1] = v.y;
        Ts[r + rr][c4 + 2] = v.z; Ts[r + rr][c4 + 3] = v.w;
    }
    __syncthreads();
#pragma unroll
    for (int rr = 0; rr < 64; rr += 16) {
        int n = r + rr;
        short4v o = { f2bf(Ts[c4 + 0][n]), f2bf(Ts[c4 + 1][n]),
                      f2bf(Ts[c4 + 2][n]), f2bf(Ts[c4 + 3][n]) };
        *reinterpret_cast<short4v*>(&wt[(size_t)(n0 + n) * K + k0 + c4]) = o;
    }
}

__global__ __launch_bounds__(256) void rope_tab_kernel(const float* __restrict__ freqs,
                                                       float* __restrict__ cost,
                                                       float* __restrict__ sint) {
    int i = blockIdx.x * 256 + threadIdx.x;  // < kS * kD/2 = 65536
    float f = freqs[i];
    float s, c;
    sincosf(f, &s, &c);
    cost[i] = c; sint[i] = s;
}

// ---------------------------------------------------------------------------
// Shared MFMA GEMM mainloop: C[128x128] tile, A [M][1024] bf16 row-major,
// Bt [N][1024] bf16 (pre-transposed weights). BK=64, 4 waves, 64x64/wave.
// ---------------------------------------------------------------------------
__device__ __forceinline__ void gemm_main(const short* __restrict__ A,
                                          const short* __restrict__ Bt,
                                          int m0, int n0, short* Als, short* Bls,
                                          f32x4 acc[4][4]) {
    const int tid = threadIdx.x, wid = tid >> 6, lane = tid & 63;
    const int srow = lane >> 3, schunk = lane & 7;
    const int fr = lane & 15, fg = lane >> 4;
    const int wm = (wid >> 1) * 64, wn = (wid & 1) * 64;
    for (int kt = 0; kt < 1024; kt += 64) {
        __syncthreads();
#pragma unroll
        for (int j = 0; j < 4; ++j) {
            int i = wid * 4 + j;
            int row = i * 8 + srow;
            gl_lds16(&A[(size_t)(m0 + row) * 1024 + kt + ((schunk ^ (row & 7)) << 3)],
                     &Als[i * 512]);
        }
#pragma unroll
        for (int j = 0; j < 4; ++j) {
            int i = wid * 4 + j;
            int row = i * 8 + srow;
            gl_lds16(&Bt[(size_t)(n0 + row) * 1024 + kt + ((schunk ^ (row & 7)) << 3)],
                     &Bls[i * 512]);
        }
        __syncthreads();
#pragma unroll
        for (int kk = 0; kk < 2; ++kk) {
            short8v af[4], bf[4];
#pragma unroll
            for (int fm = 0; fm < 4; ++fm) {
                int row = wm + fm * 16 + fr;
                af[fm] = *reinterpret_cast<const short8v*>(
                    &Als[row * 64 + (((fg + 4 * kk) ^ (row & 7)) << 3)]);
            }
#pragma unroll
            for (int fn = 0; fn < 4; ++fn) {
                int row = wn + fn * 16 + fr;
                bf[fn] = *reinterpret_cast<const short8v*>(
                    &Bls[row * 64 + (((fg + 4 * kk) ^ (row & 7)) << 3)]);
            }
#pragma unroll
            for (int fm = 0; fm < 4; ++fm)
#pragma unroll
                for (int fn = 0; fn < 4; ++fn)
                    acc[fm][fn] = mfma16(af[fm], bf[fn], acc[fm][fn]);
        }
    }
}

// ---------------------------------------------------------------------------
// Kernel: qkv = x @ W_qkv + b, fused RoPE(q,k), q pre-scaled by 1/8.
// q,k -> [B,H,S,D] bf16 ; v -> [B,H,D,S] bf16 (transposed for PV A-frags)
// ---------------------------------------------------------------------------
__global__ __launch_bounds__(256) void qkv_gemm_kernel(
    const short* __restrict__ xb, const short* __restrict__ wqt,
    const float* __restrict__ bias, const float* __restrict__ cost,
    const float* __restrict__ sint,
    short* __restrict__ qg, short* __restrict__ kg, short* __restrict__ vt) {
    __shared__ __attribute__((aligned(16))) short Als[128 * 64];
    __shared__ __attribute__((aligned(16))) short Bls[128 * 64];
    f32x4 acc[4][4] = {};
    const int tid = threadIdx.x, wid = tid >> 6, lane = tid & 63;
    const int m0 = blockIdx.y * 128, n0 = blockIdx.x * 128;
    gemm_main(xb, wqt, m0, n0, Als, Bls, acc);

    const int fr = lane & 15, fg = lane >> 4;
    const int wm = (wid >> 1) * 64, wn = (wid & 1) * 64;
    const int which = (n0 + wn) >> 10;   // 0=q 1=k 2=v (uniform per block)
    const int bidx = m0 >> 11;
#pragma unroll
    for (int fn = 0; fn < 4; ++fn) {
        int col = n0 + wn + fn * 16 + fr;
        float bv = bias[col];
        int d = col & 63;
        int h = (col >> 6) & 15;
        int p0 = d >> 1;
        int odd = d & 1;
#pragma unroll
        for (int fm = 0; fm < 4; ++fm) {
            int r0 = m0 + wm + fm * 16 + fg * 4;
            int s0 = r0 & 2047;
            float c[4];
#pragma unroll
            for (int r = 0; r < 4; ++r) c[r] = acc[fm][fn][r] + bv;
            if (which < 2) {
#pragma unroll
                for (int r = 0; r < 4; ++r) {
                    float cs = cost[(s0 + r) * 32 + p0];
                    float sn = sint[(s0 + r) * 32 + p0];
                    float p = __shfl_xor(c[r], 1);   // partner of the rope pair
                    float o = odd ? fmaf(p, sn, c[r] * cs) : fmaf(-p, sn, c[r] * cs);
                    c[r] = (which == 0) ? o * 0.125f : o;   // fold 1/sqrt(D) into q
                }
                short* dst = which ? kg : qg;
                size_t base = ((size_t)(bidx * 16 + h) * 2048 + s0) * 64 + d;
#pragma unroll
                for (int r = 0; r < 4; ++r) dst[base + (size_t)r * 64] = f2bf(c[r]);
            } else {
                short4v o = { f2bf(c[0]), f2bf(c[1]), f2bf(c[2]), f2bf(c[3]) };
                *reinterpret_cast<short4v*>(
                    &vt[((size_t)(bidx * 16 + h) * 64 + d) * 2048 + s0]) = o;
            }
        }
    }
}

// ---------------------------------------------------------------------------
// Kernel: MFMA flash attention, 32x32 fragments, swapped operands.
// Block = (b,h) x 128 q-rows, 4 waves x 32 q-rows. KVBLK=64, double-buffered.
// S^T = mfma(K, Q): lane q = lane&31, keys in regs. Softmax fully in-register.
// P -> PV B-frag via cvt_pk + shfl_xor(32). O^T = mfma(V^T, P^T).
// ---------------------------------------------------------------------------
__global__ __launch_bounds__(256) void attn_mfma_kernel(
    const short* __restrict__ qg, const short* __restrict__ kg,
    const short* __restrict__ vt, short* __restrict__ ab) {
    __shared__ __attribute__((aligned(16))) short KV[2][8192];  // [buf][K 64x64 | V 64x64]
    const int tid = threadIdx.x, wid = tid >> 6, lane = tid & 63;
    const int l31 = lane & 31, hi = lane >> 5;
    const int sw = 8 * (l31 & 7);
    const int bh = blockIdx.y;
    const int qw = blockIdx.x * 128 + wid * 32;
    const short* qb = qg + (size_t)bh * 2048 * 64;
    const short* kb = kg + (size_t)bh * 2048 * 64;
    const short* vb = vt + (size_t)bh * 64 * 2048;

    // Q B-fragments: col=q=lane&31, k-elems d = kkq*16 + hi*8 + e
    short8v qf[4];
#pragma unroll
    for (int kkq = 0; kkq < 4; ++kkq)
        qf[kkq] = *reinterpret_cast<const short8v*>(
            &qb[(size_t)(qw + l31) * 64 + kkq * 16 + hi * 8]);

    f32x16 o[2] = {};
    float m_i = -INFINITY, l_i = 0.f;

    const int wrow = lane >> 3, wcol = lane & 7;
    const int soff = 8 * (wcol ^ wrow);   // pre-swizzled source chunk (16B units)

    // prologue: stage tile 0 into buf 0
#pragma unroll
    for (int j = 0; j < 2; ++j) {
        int r0 = wid * 16 + j * 8;
        gl_lds16(&kb[(size_t)(r0 + wrow) * 64 + soff], &KV[0][r0 * 64]);
        gl_lds16(&vb[(size_t)(r0 + wrow) * 2048 + soff], &KV[0][4096 + r0 * 64]);
    }
    __syncthreads();

    for (int t = 0; t < 32; ++t) {
        const int buf = t & 1;
        if (t + 1 < 32) {   // stage next tile into other buffer (overlaps compute)
            int kt2 = (t + 1) * 64;
#pragma unroll
            for (int j = 0; j < 2; ++j) {
                int r0 = wid * 16 + j * 8;
                gl_lds16(&kb[(size_t)(kt2 + r0 + wrow) * 64 + soff],
                         &KV[buf ^ 1][r0 * 64]);
                gl_lds16(&vb[(size_t)(r0 + wrow) * 2048 + kt2 + soff],
                         &KV[buf ^ 1][4096 + r0 * 64]);
            }
        }
        const short* Kb = &KV[buf][0];
        const short* Vb = &KV[buf][4096];

        // S^T = K Q^T : sacc[f] covers keys f*32..f*32+32 for q = lane&31
        f32x16 sacc[2];
#pragma unroll
        for (int r = 0; r < 16; ++r) { sacc[0][r] = 0.f; sacc[1][r] = 0.f; }
#pragma unroll
        for (int kkq = 0; kkq < 4; ++kkq) {
            int off = kkq * 16 + hi * 8;
            short8v a0 = *reinterpret_cast<const short8v*>(&Kb[l31 * 64 + (off ^ sw)]);
            short8v a1 = *reinterpret_cast<const short8v*>(&Kb[(32 + l31) * 64 + (off ^ sw)]);
            sacc[0] = mfma32(a0, qf[kkq], sacc[0]);
            sacc[1] = mfma32(a1, qf[kkq], sacc[1]);
        }

        // online softmax, fully per-lane (row = q = lane&31; halves share via xor 32)
        float pmax = sacc[0][0];
#pragma unroll
        for (int r = 1; r < 16; ++r) pmax = fmaxf(pmax, sacc[0][r]);
#pragma unroll
        for (int r = 0; r < 16; ++r) pmax = fmaxf(pmax, sacc[1][r]);
        pmax = fmaxf(pmax, __shfl_xor(pmax, 32));
        float mnew = fmaxf(m_i, pmax);
        float al = __expf(m_i - mnew);
        m_i = mnew;
        float rs = 0.f;
#pragma unroll
        for (int r = 0; r < 16; ++r) { float p = __expf(sacc[0][r] - mnew); sacc[0][r] = p; rs += p; }
#pragma unroll
        for (int r = 0; r < 16; ++r) { float p = __expf(sacc[1][r] - mnew); sacc[1][r] = p; rs += p; }
        rs += __shfl_xor(rs, 32);
        l_i = l_i * al + rs;
#pragma unroll
        for (int r = 0; r < 16; ++r) { o[0][r] *= al; o[1][r] *= al; }

        // P: C-layout -> B-frag layout via cvt_pk + 1-hop lane32 exchange
        short8v pb[4];
#pragma unroll
        for (int f = 0; f < 2; ++f) {
            unsigned c[8];
#pragma unroll
            for (int i = 0; i < 8; ++i)
                c[i] = pk_bf16(sacc[f][2 * i], sacc[f][2 * i + 1]);
#pragma unroll
            for (int hf = 0; hf < 2; ++hf) {
                unsigned a0 = c[hf * 4 + 0], a1 = c[hf * 4 + 1];
                unsigned a2 = c[hf * 4 + 2], a3 = c[hf * 4 + 3];
                unsigned s0x = (unsigned)__shfl_xor((int)a0, 32);
                unsigned s1x = (unsigned)__shfl_xor((int)a1, 32);
                unsigned s2x = (unsigned)__shfl_xor((int)a2, 32);
                unsigned s3x = (unsigned)__shfl_xor((int)a3, 32);
                uint4 w;
                w.x = hi ? s2x : a0;
                w.y = hi ? s3x : a1;
                w.z = hi ? a2 : s0x;
                w.w = hi ? a3 : s1x;
                pb[f * 2 + hf] = __builtin_bit_cast(short8v, w);
            }
        }

        // O^T += V^T P^T : o[fd] covers d = fd*32..+32, col=q=lane&31
#pragma unroll
        for (int kk = 0; kk < 4; ++kk) {
            int off = kk * 16 + hi * 8;
            short8v v0 = *reinterpret_cast<const short8v*>(&Vb[l31 * 64 + (off ^ sw)]);
            short8v v1 = *reinterpret_cast<const short8v*>(&Vb[(32 + l31) * 64 + (off ^ sw)]);
            o[0] = mfma32(v0, pb[kk], o[0]);
            o[1] = mfma32(v1, pb[kk], o[1]);
        }
        __syncthreads();   // waits vmcnt(0): next-tile stage complete; buf reads done
    }

    // epilogue: normalize, transpose via (now free) LDS, coalesced bf16 store
    const float inv = 1.f / l_i;
    short* ep = &KV[0][wid * 2048];    // per-wave 32x64 bf16 tile, XOR-swizzled
    const int q = l31;
#pragma unroll
    for (int fd = 0; fd < 2; ++fd)
#pragma unroll
        for (int i = 0; i < 4; ++i) {
            int d0 = fd * 32 + 8 * i + 4 * hi;   // 4 consecutive d at d0
            uint2 w;
            w.x = pk_bf16(o[fd][4 * i + 0] * inv, o[fd][4 * i + 1] * inv);
            w.y = pk_bf16(o[fd][4 * i + 2] * inv, o[fd][4 * i + 3] * inv);
            *reinterpret_cast<uint2*>(&ep[q * 64 + (d0 ^ (8 * (q & 3)))]) = w;
        }
    __syncthreads();
    const int bb = bh >> 4, hh = bh & 15;
#pragma unroll
    for (int j = 0; j < 4; ++j) {
        int row = j * 8 + wrow;
        short8v tv = *reinterpret_cast<const short8v*>(
            &ep[row * 64 + ((8 * wcol) ^ (8 * (row & 3)))]);
        int s = qw + row;
        *reinterpret_cast<short8v*>(
            &ab[(size_t)(bb * 2048 + s) * 1024 + hh * 64 + 8 * wcol]) = tv;
    }
}

// ---------------------------------------------------------------------------
// Kernel: out = attn_out @ W_out + b_out  (f32 output)
// ---------------------------------------------------------------------------
__global__ __launch_bounds__(256) void out_gemm_kernel(
    const short* __restrict__ ab, const short* __restrict__ wot,
    const float* __restrict__ bias, float* __restrict__ out) {
    __shared__ __attribute__((aligned(16))) short Als[128 * 64];
    __shared__ __attribute__((aligned(16))) short Bls[128 * 64];
    f32x4 acc[4][4] = {};
    const int tid = threadIdx.x, wid = tid >> 6, lane = tid & 63;
    const int m0 = blockIdx.y * 128, n0 = blockIdx.x * 128;
    gemm_main(ab, wot, m0, n0, Als, Bls, acc);
    const int fr = lane & 15, fg = lane >> 4;
    const int wm = (wid >> 1) * 64, wn = (wid & 1) * 64;
#pragma unroll
    for (int fn = 0; fn < 4; ++fn) {
        int col = n0 + wn + fn * 16 + fr;
        float bv = bias[col];
#pragma unroll
        for (int fm = 0; fm < 4; ++fm) {
            int r0 = m0 + wm + fm * 16 + fg * 4;
#pragma unroll
            for (int r = 0; r < 4; ++r)
                out[(size_t)(r0 + r) * 1024 + col] = acc[fm][fn][r] + bv;
        }
    }
}

// ---------------------------------------------------------------------------
extern "C" void kernel_launch(void* const* d_in, const int* in_sizes, int n_in,
                              void* d_out, int out_size, void* d_ws, size_t ws_size,
                              hipStream_t stream) {
    const float* x     = (const float*)d_in[0];
    const float* freqs = (const float*)d_in[1];
    const float* W_qkv = (const float*)d_in[2];
    const float* b_qkv = (const float*)d_in[3];
    const float* W_out = (const float*)d_in[4];
    const float* b_out = (const float*)d_in[5];
    float* out = (float*)d_out;

    char* w = (char*)d_ws;
    short* xb  = (short*)w;  w += (size_t)kT * kC * 2;          // 8 MiB
    short* wqt = (short*)w;  w += (size_t)kF * kC * 2;          // 6 MiB
    short* wot = (short*)w;  w += (size_t)kC * kC * 2;          // 2 MiB
    short* qgw = (short*)w;  w += (size_t)kB * kH * kS * kD * 2;
    short* kgw = (short*)w;  w += (size_t)kB * kH * kS * kD * 2;
    short* vtw = (short*)w;  w += (size_t)kB * kH * kS * kD * 2;
    short* abw = (short*)w;  w += (size_t)kT * kC * 2;
    float* costt = (float*)w; w += (size_t)kS * (kD / 2) * 4;
    float* sintt = (float*)w; w += (size_t)kS * (kD / 2) * 4;

    cvt_x_kernel<<<dim3(kT * kC / 1024), 256, 0, stream>>>(x, xb, kT * kC / 4);
    tcvt_kernel<<<dim3(kF / 64, kC / 64), 256, 0, stream>>>(W_qkv, wqt, kC, kF);
    tcvt_kernel<<<dim3(kC / 64, kC / 64), 256, 0, stream>>>(W_out, wot, kC, kC);
    rope_tab_kernel<<<dim3(kS * (kD / 2) / 256), 256, 0, stream>>>(freqs, costt, sintt);

    qkv_gemm_kernel<<<dim3(kF / 128, kT / 128), 256, 0, stream>>>(
        xb, wqt, b_qkv, costt, sintt, qgw, kgw, vtw);
    attn_mfma_kernel<<<dim3(kS / 128, kB * kH), 256, 0, stream>>>(qgw, kgw, vtw, abw);
    out_gemm_kernel<<<dim3(kC / 128, kT / 128), 256, 0, stream>>>(abw, wot, b_out, out);
}